// Round 3
// baseline (262.923 us; speedup 1.0000x reference)
//
#include <hip/hip_runtime.h>

// Problem constants (from reference): B=32, CIN=64, COUT=64, H=W=128, 1x1 conv
#define CIN   64
#define COUT  64
#define HW    16384          // 128*128
#define HW4   4096           // HW/4 (int4 units)
#define NPIX  (32 * HW)      // B * H * W = 524288

typedef int   v4i __attribute__((ext_vector_type(4)));

// ---------------------------------------------------------------------------
// Prep kernel: pack weights to int8 dwords + fold requant params.
// wp[o*16 + k] holds (w[o][4k..4k+3] - wzp[o]) as 4 signed bytes.
// params[o] = { scale_o, bias_o/os + ozp, as_float(sum_ci(w'-wzp)), 0 }
// ---------------------------------------------------------------------------
__global__ void prep_kernel(const int* __restrict__ w,
                            const float* __restrict__ wscale,
                            const int* __restrict__ wzp,
                            const float* __restrict__ bias,
                            const float* __restrict__ is_p,
                            const float* __restrict__ os_p,
                            const int* __restrict__ ozp_p,
                            int* __restrict__ wp,
                            float4* __restrict__ params) {
    int o = threadIdx.x;
    if (o >= COUT) return;
    int zp = wzp[o];
    int sum = 0;
    #pragma unroll
    for (int k = 0; k < 16; ++k) {
        int c0 = w[o * CIN + 4 * k + 0] - zp;
        int c1 = w[o * CIN + 4 * k + 1] - zp;
        int c2 = w[o * CIN + 4 * k + 2] - zp;
        int c3 = w[o * CIN + 4 * k + 3] - zp;
        sum += c0 + c1 + c2 + c3;
        wp[o * 16 + k] = (c0 & 0xff) | ((c1 & 0xff) << 8) |
                         ((c2 & 0xff) << 16) | ((c3 & 0xff) << 24);
    }
    float scale = is_p[0] * wscale[o] / os_p[0];
    float bterm = bias[o] / os_p[0] + (float)ozp_p[0];
    float4 pr;
    pr.x = scale;
    pr.y = bterm;
    pr.z = __int_as_float(sum);
    pr.w = 0.0f;
    params[o] = pr;
}

// ---------------------------------------------------------------------------
// Main kernel: 4 consecutive pixels / thread (512 blocks x 256 threads).
// All VMEM is dwordx4: 64 int4 loads (16B/lane x 64 lanes = 1KiB/instr) and
// 64 int4 nontemporal stores per thread.
//
// ROUND-2 POST-MORTEM FIX: __launch_bounds__ min-waves only sets a VGPR
// *cap*; the allocator's occupancy heuristic still targeted 8 waves/EU
// (<=64 VGPR, got 44) and off-loaded the 64-dword px array to AGPR/scratch
// — both prior rounds tested "4px + off-loaded px", never the intended
// register-resident version. amdgpu_waves_per_eu(2,2) pins min AND max,
// making 2 waves/EU the allocator's *target* so px stays in arch VGPRs.
// 512 blocks = 2 blocks/CU = exactly 2 waves/SIMD.
// GATE: VGPR_Count must come back >=~110, else this arc is dead.
// ---------------------------------------------------------------------------
__global__ __launch_bounds__(256)
__attribute__((amdgpu_waves_per_eu(2, 2)))
void conv_kernel(
    const int* __restrict__ x,
    const int* __restrict__ wp_g,
    const float4* __restrict__ params_g,
    const int* __restrict__ izp_p,
    int* __restrict__ out) {

    __shared__ int4   s_wp[COUT * 4];   // 64 outs x 16 dwords (as 4x int4) = 4 KB
    __shared__ float4 s_par[COUT];      // 1 KB

    int tid = threadIdx.x;
    // stage weights: 256 int4 = 1024 dwords, one per thread
    s_wp[tid] = ((const int4*)wp_g)[tid];
    if (tid < COUT) s_par[tid] = params_g[tid];
    int izp_adj = izp_p[0] - 128;       // 0 for the reference inputs; exact otherwise
    __syncthreads();

    int t = blockIdx.x * 256 + tid;     // quad index 0..131071
    int b = t >> 12;                    // / (HW/4): 4096 quads per image
    int q = t & (HW4 - 1);              // quad within image (pixel = 4*q)

    const v4i* xb = (const v4i*)(x + b * (CIN * HW)) + q;

    // px{j}[cg]: for pixel j of the quad, channel group cg (4 channels packed
    // as signed bytes (x-128) — byte XOR 0x80 trick on 0..255 values)
    int px0[16], px1[16], px2[16], px3[16];
    #pragma unroll
    for (int cg = 0; cg < 16; ++cg) {
        v4i v0 = xb[(4 * cg + 0) * HW4];   // channel 4cg+0, pixels 4q..4q+3
        v4i v1 = xb[(4 * cg + 1) * HW4];
        v4i v2 = xb[(4 * cg + 2) * HW4];
        v4i v3 = xb[(4 * cg + 3) * HW4];
        px0[cg] = (v0.x | (v1.x << 8) | (v2.x << 16) | (v3.x << 24)) ^ 0x80808080;
        px1[cg] = (v0.y | (v1.y << 8) | (v2.y << 16) | (v3.y << 24)) ^ 0x80808080;
        px2[cg] = (v0.z | (v1.z << 8) | (v2.z << 16) | (v3.z << 24)) ^ 0x80808080;
        px3[cg] = (v0.w | (v1.w << 8) | (v2.w << 16) | (v3.w << 24)) ^ 0x80808080;
    }

    v4i* ob = (v4i*)(out + b * (COUT * HW)) + q;

    // unroll 2: ILP inside each o comes from the 4 independent sdot4 chains
    #pragma unroll 2
    for (int o = 0; o < COUT; ++o) {
        int wv[16];
        *(int4*)(&wv[0])  = s_wp[o * 4 + 0];
        *(int4*)(&wv[4])  = s_wp[o * 4 + 1];
        *(int4*)(&wv[8])  = s_wp[o * 4 + 2];
        *(int4*)(&wv[12]) = s_wp[o * 4 + 3];
        float4 pr = s_par[o];
        int wsum = __float_as_int(pr.z);
        int base = -izp_adj * wsum;      // izp correction (0 here)

        int a0 = base, a1 = base, a2 = base, a3 = base;
        #pragma unroll
        for (int cg = 0; cg < 16; ++cg) {
            a0 = __builtin_amdgcn_sdot4(px0[cg], wv[cg], a0, false);
            a1 = __builtin_amdgcn_sdot4(px1[cg], wv[cg], a1, false);
            a2 = __builtin_amdgcn_sdot4(px2[cg], wv[cg], a2, false);
            a3 = __builtin_amdgcn_sdot4(px3[cg], wv[cg], a3, false);
        }

        float f0 = fmaf((float)a0, pr.x, pr.y);
        float f1 = fmaf((float)a1, pr.x, pr.y);
        float f2 = fmaf((float)a2, pr.x, pr.y);
        float f3 = fmaf((float)a3, pr.x, pr.y);
        f0 = fminf(fmaxf(rintf(f0), 0.0f), 255.0f);   // v_rndne matches jnp.round
        f1 = fminf(fmaxf(rintf(f1), 0.0f), 255.0f);
        f2 = fminf(fmaxf(rintf(f2), 0.0f), 255.0f);
        f3 = fminf(fmaxf(rintf(f3), 0.0f), 255.0f);

        v4i r;
        r.x = (int)f0; r.y = (int)f1; r.z = (int)f2; r.w = (int)f3;
        __builtin_nontemporal_store(r, ob + o * HW4);  // write-once stream
    }
}

extern "C" void kernel_launch(void* const* d_in, const int* in_sizes, int n_in,
                              void* d_out, int out_size, void* d_ws, size_t ws_size,
                              hipStream_t stream) {
    const int*   x      = (const int*)d_in[0];     // [32,64,128,128] int32 (uint8 vals)
    const float* is_p   = (const float*)d_in[1];   // input_scale
    const int*   izp_p  = (const int*)d_in[2];     // input_zero_point
    const int*   w      = (const int*)d_in[3];     // [64,64,1,1] int32
    const float* wscale = (const float*)d_in[4];   // [64]
    const int*   wzp    = (const int*)d_in[5];     // [64]
    const float* bias   = (const float*)d_in[6];   // [64]
    const float* os_p   = (const float*)d_in[7];   // output_scale
    const int*   ozp_p  = (const int*)d_in[8];     // output_zero_point

    int* out = (int*)d_out;

    int*    wp     = (int*)d_ws;                       // 4096 B
    float4* params = (float4*)((char*)d_ws + 4096);    // 1024 B

    prep_kernel<<<1, 64, 0, stream>>>(w, wscale, wzp, bias, is_p, os_p, ozp_p, wp, params);

    // 524288 pixels / 4 per thread / 256 per block = 512 blocks
    conv_kernel<<<512, 256, 0, stream>>>(x, wp, params, izp_p, out);
}

// Round 4
// 253.930 us; speedup vs baseline: 1.0354x; 1.0354x over previous
//
#include <hip/hip_runtime.h>

// Problem constants (from reference): B=32, CIN=64, COUT=64, H=W=128, 1x1 conv
#define CIN   64
#define COUT  64
#define HW    16384          // 128*128
#define PXB   128            // pixels per block (= block threads)
#define NPIX  (32 * HW)      // 524288

// ---------------------------------------------------------------------------
// Prep kernel: pack weights to int8 dwords + fold requant params.
// wp[o*16 + k] holds (w[o][4k..4k+3] - wzp[o]) as 4 signed bytes.
// params[o] = { scale_o, bias_o/os + ozp, as_float(sum_ci(w'-wzp)), 0 }
// ---------------------------------------------------------------------------
__global__ void prep_kernel(const int* __restrict__ w,
                            const float* __restrict__ wscale,
                            const int* __restrict__ wzp,
                            const float* __restrict__ bias,
                            const float* __restrict__ is_p,
                            const float* __restrict__ os_p,
                            const int* __restrict__ ozp_p,
                            int* __restrict__ wp,
                            float4* __restrict__ params) {
    int o = threadIdx.x;
    if (o >= COUT) return;
    int zp = wzp[o];
    int sum = 0;
    #pragma unroll
    for (int k = 0; k < 16; ++k) {
        int c0 = w[o * CIN + 4 * k + 0] - zp;
        int c1 = w[o * CIN + 4 * k + 1] - zp;
        int c2 = w[o * CIN + 4 * k + 2] - zp;
        int c3 = w[o * CIN + 4 * k + 3] - zp;
        sum += c0 + c1 + c2 + c3;
        wp[o * 16 + k] = (c0 & 0xff) | ((c1 & 0xff) << 8) |
                         ((c2 & 0xff) << 16) | ((c3 & 0xff) << 24);
    }
    float scale = is_p[0] * wscale[o] / os_p[0];
    float bterm = bias[o] / os_p[0] + (float)ozp_p[0];
    float4 pr;
    pr.x = scale;
    pr.y = bterm;
    pr.z = __int_as_float(sum);
    pr.w = 0.0f;
    params[o] = pr;
}

// ---------------------------------------------------------------------------
// Main kernel: 1 pixel/thread compute (round-0's proven body), but x is
// staged into LDS via ASYNC global_load_lds width=16 — no destination
// VGPRs, so each wave keeps its whole 16 KB half-tile in flight
// regardless of register budget. This is the fix for the latency-bound
// regime (2.4 of 6.3 TB/s) that rounds 1-3 failed to reach via
// register-resident multi-pixel (allocator refused >88 VGPRs, spilled).
//
// Block = 128 threads = 128 pixels. LDS x-tile s_x[c][p] = 32 KB.
// Stage: 16 instrs/wave, each 16 B/lane = 1 KB = 2 channel rows
// (lanes 0-31 -> channel c, lanes 32-63 -> channel c+1; per-lane global
// addresses, linear wave-uniform LDS dest — matches [c][p] exactly).
// ~38 KB LDS/block -> 4 blocks/CU resident; blocks out of phase give
// cross-block load/compute overlap (32 KB outstanding/block >> the
// ~9 KB/CU needed for 6.3 TB/s).
// Compute gather from LDS: bank = tid&31 -> 2 lanes/bank = conflict-free.
// ---------------------------------------------------------------------------
__global__ __launch_bounds__(128) void conv_kernel(
    const int* __restrict__ x,
    const int* __restrict__ wp_g,
    const float4* __restrict__ params_g,
    const int* __restrict__ izp_p,
    int* __restrict__ out) {

    __shared__ int    s_x[CIN * PXB];   // [c][p] dwords, 32 KB
    __shared__ int4   s_wp[COUT * 4];   // 4 KB
    __shared__ float4 s_par[COUT];      // 1 KB

    const int tid  = threadIdx.x;       // 0..127
    const int wave = tid >> 6;          // 0..1
    const int lane = tid & 63;

    const int t0 = blockIdx.x * PXB;    // first pixel of the block
    const int b  = t0 >> 14;            // / HW  (HW/PXB = 128 blocks per image, no straddle)
    const int p0 = t0 & (HW - 1);
    const int* xb = x + b * (CIN * HW) + p0;

    // ---- async stage x-tile: issue FIRST so HBM reads start immediately.
    // instr j of wave w covers channel pair c = 2*(w*16+j):
    //   global: lane 0-31 read 16B of row c, lane 32-63 16B of row c+1
    //   LDS:    linear base + lane*16 = s_x[c][0..127] ++ s_x[c+1][0..127]
    #pragma unroll
    for (int j = 0; j < 16; ++j) {
        const int c  = (wave * 16 + j) * 2;
        const int cl = c + (lane >> 5);
        const int* gp = xb + cl * HW + (lane & 31) * 4;   // 16B-aligned (p0 is x128)
        __builtin_amdgcn_global_load_lds(
            (const __attribute__((address_space(1))) int*)gp,
            (__attribute__((address_space(3))) int*)&s_x[c * PXB],
            16, 0, 0);
    }

    // weights/params via normal LDS writes — overlap with the async loads
    s_wp[tid]       = ((const int4*)wp_g)[tid];
    s_wp[tid + 128] = ((const int4*)wp_g)[tid + 128];
    if (tid < COUT) s_par[tid] = params_g[tid];
    const int izp_adj = izp_p[0] - 128;   // 0 for reference inputs; exact otherwise

    __syncthreads();   // compiler emits vmcnt(0)+lgkmcnt(0) drain before s_barrier

    // ---- pack this thread's pixel: 64 ds_read_b32, bank-conflict-free
    int px[16];
    #pragma unroll
    for (int cg = 0; cg < 16; ++cg) {
        int v0 = s_x[(4 * cg + 0) * PXB + tid];
        int v1 = s_x[(4 * cg + 1) * PXB + tid];
        int v2 = s_x[(4 * cg + 2) * PXB + tid];
        int v3 = s_x[(4 * cg + 3) * PXB + tid];
        // values 0..255 in low byte; (x-128) as int8 == byte XOR 0x80
        px[cg] = (v0 | (v1 << 8) | (v2 << 16) | (v3 << 24)) ^ 0x80808080;
    }

    int* ob = out + b * (COUT * HW) + p0 + tid;

    #pragma unroll 8
    for (int o = 0; o < COUT; ++o) {
        int4 w0 = s_wp[o * 4 + 0];
        int4 w1 = s_wp[o * 4 + 1];
        int4 w2 = s_wp[o * 4 + 2];
        int4 w3 = s_wp[o * 4 + 3];
        float4 pr = s_par[o];
        int wsum = __float_as_int(pr.z);
        int acc = -izp_adj * wsum;      // izp correction (0 here)

        acc = __builtin_amdgcn_sdot4(px[0],  w0.x, acc, false);
        acc = __builtin_amdgcn_sdot4(px[1],  w0.y, acc, false);
        acc = __builtin_amdgcn_sdot4(px[2],  w0.z, acc, false);
        acc = __builtin_amdgcn_sdot4(px[3],  w0.w, acc, false);
        acc = __builtin_amdgcn_sdot4(px[4],  w1.x, acc, false);
        acc = __builtin_amdgcn_sdot4(px[5],  w1.y, acc, false);
        acc = __builtin_amdgcn_sdot4(px[6],  w1.z, acc, false);
        acc = __builtin_amdgcn_sdot4(px[7],  w1.w, acc, false);
        acc = __builtin_amdgcn_sdot4(px[8],  w2.x, acc, false);
        acc = __builtin_amdgcn_sdot4(px[9],  w2.y, acc, false);
        acc = __builtin_amdgcn_sdot4(px[10], w2.z, acc, false);
        acc = __builtin_amdgcn_sdot4(px[11], w2.w, acc, false);
        acc = __builtin_amdgcn_sdot4(px[12], w3.x, acc, false);
        acc = __builtin_amdgcn_sdot4(px[13], w3.y, acc, false);
        acc = __builtin_amdgcn_sdot4(px[14], w3.z, acc, false);
        acc = __builtin_amdgcn_sdot4(px[15], w3.w, acc, false);

        float f = fmaf((float)acc, pr.x, pr.y);
        f = rintf(f);                         // v_rndne matches jnp.round
        f = fminf(fmaxf(f, 0.0f), 255.0f);    // clamp to uint8 range
        __builtin_nontemporal_store((int)f, ob + o * HW);  // write-once stream
    }
}

extern "C" void kernel_launch(void* const* d_in, const int* in_sizes, int n_in,
                              void* d_out, int out_size, void* d_ws, size_t ws_size,
                              hipStream_t stream) {
    const int*   x      = (const int*)d_in[0];     // [32,64,128,128] int32 (uint8 vals)
    const float* is_p   = (const float*)d_in[1];   // input_scale
    const int*   izp_p  = (const int*)d_in[2];     // input_zero_point
    const int*   w      = (const int*)d_in[3];     // [64,64,1,1] int32
    const float* wscale = (const float*)d_in[4];   // [64]
    const int*   wzp    = (const int*)d_in[5];     // [64]
    const float* bias   = (const float*)d_in[6];   // [64]
    const float* os_p   = (const float*)d_in[7];   // output_scale
    const int*   ozp_p  = (const int*)d_in[8];     // output_zero_point

    int* out = (int*)d_out;

    int*    wp     = (int*)d_ws;                       // 4096 B
    float4* params = (float4*)((char*)d_ws + 4096);    // 1024 B

    prep_kernel<<<1, 64, 0, stream>>>(w, wscale, wzp, bias, is_p, os_p, ozp_p, wp, params);

    // 524288 pixels / 128 per block = 4096 blocks x 128 threads
    conv_kernel<<<4096, 128, 0, stream>>>(x, wp, params, izp_p, out);
}